// Round 1
// 645.775 us; speedup vs baseline: 1.0644x; 1.0644x over previous
//
#include <hip/hip_runtime.h>
#include <cstddef>
#include <cstdint>
#include <math.h>

#define N_NODES 50000
#define N_EDGES 1600000
#define IN_C 512
#define HID_C 256
#define OUT_C 50
#define PAD_C 64
#define NUM_LAYERS 10
#define NBUCK 98          // ceil(50000/512) row-buckets
#define BSHIFT 9          // 512 rows per bucket
#define BCAP 20480        // mean 16327 + 32 sigma — overflow unreachable
#define PHB_CHUNK 8192    // edges per block in bucket_scatter
#define PHB_BLOCKS 196    // ceil(N_EDGES / PHB_CHUNK)

typedef __attribute__((ext_vector_type(8))) short short8;    // 8 bf16 (4 VGPRs)
typedef __attribute__((ext_vector_type(4))) float floatx4;   // MFMA C/D frag

__device__ inline unsigned short f2bf(float f) {             // RNE fp32->bf16
    unsigned int u = __float_as_uint(f);
    u += 0x7fffu + ((u >> 16) & 1u);
    return (unsigned short)(u >> 16);
}

// async 16B global->LDS (no VGPR round-trip; compiler cannot collapse this)
#define ASYNC16(g, l)                                                     \
    __builtin_amdgcn_global_load_lds(                                     \
        (const __attribute__((address_space(1))) void*)(g),               \
        (__attribute__((address_space(3))) void*)(l), 16, 0, 0)

// ---------------------------------------------------------------------------
// W1 [512,256] fp32  ->  Wt [256,512] bf16   (LDS-tiled transpose)
// ---------------------------------------------------------------------------
__global__ __launch_bounds__(256) void transpose_w1(const float* __restrict__ W1,
                                                    unsigned short* __restrict__ Wt) {
    __shared__ float tile[32][33];
    int bx = blockIdx.x;               // k-tile (16)
    int by = blockIdx.y;               // n-tile (8)
    int tx = threadIdx.x & 31, ty = threadIdx.x >> 5;   // 32 x 8
#pragma unroll
    for (int i = 0; i < 32; i += 8)
        tile[ty + i][tx] = W1[(bx * 32 + ty + i) * HID_C + by * 32 + tx];
    __syncthreads();
#pragma unroll
    for (int i = 0; i < 32; i += 8)
        Wt[(size_t)(by * 32 + ty + i) * IN_C + bx * 32 + tx] = f2bf(tile[tx][ty + i]);
}

// ---------------------------------------------------------------------------
// GEMM1 v3: h_hid[M,256] = relu(x[M,512] @ W1 + b1)
// Tile 64 x 256 (full N -> A read exactly once), BK=32, double-buffered LDS,
// ALL staging via global_load_lds (async, zero VGPR -> pipeline can't be
// collapsed by regalloc; old version's VGPR_Count=52 proved the register
// prefetch was dead). A staged as fp32 with XOR-swizzled per-lane SOURCE
// (linear LDS dest, m173 pattern) so the 128B-row-stride ds_read_b128 spreads
// evenly over banks; bf16 cvt happens on the LDS->reg read side. B (bf16,
// 64B rows) is naturally conflict-free linear. One barrier per K-step.
// Wave grid 2x2: per wave 32 rows x 128 cols, acc[2][8].
// ---------------------------------------------------------------------------
__global__ __launch_bounds__(256) void gemm1_mfma(const float* __restrict__ A,
                                                  const unsigned short* __restrict__ Wt,
                                                  const float* __restrict__ bias,
                                                  float* __restrict__ C) {
    __shared__ float          As[2][64 * 32];      // 8 KB per buffer (fp32)
    __shared__ unsigned short Bs[2][256 * 32];     // 16 KB per buffer (bf16)
    const int tid  = threadIdx.x;
    const int wave = tid >> 6, lane = tid & 63;
    const int quad = lane >> 4, l16 = lane & 15;
    const int m0 = blockIdx.x * 64;
    const int wm = (wave >> 1) * 32;               // row offset of this wave
    const int wn = (wave & 1) * 128;               // col offset of this wave

    floatx4 acc[2][8];
#pragma unroll
    for (int i = 0; i < 2; ++i)
#pragma unroll
        for (int j = 0; j < 8; ++j) acc[i][j] = (floatx4){0.f, 0.f, 0.f, 0.f};

    // stage one BK=32 slab of A (64x32 fp32) + B (256x32 bf16) into buf
    auto stage = [&](int buf, int k0) {
        // A: 512 16B-slots; slot=(r,c), c in [0,8). LDS linear; SOURCE chunk
        // is c ^ (r&7) so the read-side XOR lands on the right data.
#pragma unroll
        for (int j = 0; j < 2; ++j) {
            int slot = tid + j * 256;
            int r = slot >> 3, c = slot & 7;
            int gr = m0 + r;
            if (gr >= N_NODES) gr = N_NODES - 1;   // clamp: finite garbage, masked at C-write
            const float* src = A + (size_t)gr * IN_C + k0 + ((c ^ (r & 7)) << 2);
            ASYNC16(src, &As[buf][slot << 2]);
        }
        // B: 1024 16B-slots; slot=(n,c), c in [0,4). Fully linear.
#pragma unroll
        for (int j = 0; j < 4; ++j) {
            int slot = tid + j * 256;
            int n = slot >> 2, c = slot & 3;
            const unsigned short* src = Wt + (size_t)n * IN_C + k0 + (c << 3);
            ASYNC16(src, &Bs[buf][slot << 3]);
        }
    };

    auto compute = [&](int buf) {
        short8 bfr[8], afr[2];
#pragma unroll
        for (int nt = 0; nt < 8; ++nt) {
            int n = wn + nt * 16 + l16;
            bfr[nt] = *(const short8*)&Bs[buf][(n << 5) + (quad << 3)];
        }
#pragma unroll
        for (int mt = 0; mt < 2; ++mt) {
            int r  = wm + mt * 16 + l16;
            int rx = r & 7;
            float4 lo = *(const float4*)&As[buf][(r << 5) + (((2 * quad)     ^ rx) << 2)];
            float4 hi = *(const float4*)&As[buf][(r << 5) + (((2 * quad + 1) ^ rx) << 2)];
            short8 a;
            a[0] = (short)f2bf(lo.x); a[1] = (short)f2bf(lo.y);
            a[2] = (short)f2bf(lo.z); a[3] = (short)f2bf(lo.w);
            a[4] = (short)f2bf(hi.x); a[5] = (short)f2bf(hi.y);
            a[6] = (short)f2bf(hi.z); a[7] = (short)f2bf(hi.w);
            afr[mt] = a;
        }
#pragma unroll
        for (int mt = 0; mt < 2; ++mt)
#pragma unroll
            for (int nt = 0; nt < 8; ++nt)
                acc[mt][nt] = __builtin_amdgcn_mfma_f32_16x16x32_bf16(afr[mt], bfr[nt],
                                                                      acc[mt][nt], 0, 0, 0);
    };

    stage(0, 0);
    __syncthreads();                     // vmcnt(0) drain + barrier: buf0 ready
    int buf = 0;
    for (int ks = 0; ks < IN_C / 32; ++ks) {
        if (ks + 1 < IN_C / 32) stage(buf ^ 1, (ks + 1) * 32);   // async, in flight over MFMA
        compute(buf);
        __syncthreads();                 // drains this iter's loads; reads of buf retired
        buf ^= 1;
    }

    // epilogue: row = quad*4+r, col = l16 (verified mapping, unchanged)
#pragma unroll
    for (int nt = 0; nt < 8; ++nt) {
        int n = wn + nt * 16 + l16;
        float bn = bias[n];
#pragma unroll
        for (int mt = 0; mt < 2; ++mt) {
#pragma unroll
            for (int r = 0; r < 4; ++r) {
                int m = m0 + wm + mt * 16 + quad * 4 + r;
                if (m < N_NODES) {
                    float v = acc[mt][nt][r] + bn;
                    C[(size_t)m * HID_C + n] = v > 0.f ? v : 0.f;
                }
            }
        }
    }
}

// ---------------------------------------------------------------------------
// pad W2 [256,50] -> Wp [256,64] (zeros), b2 -> bp[64]
// ---------------------------------------------------------------------------
__global__ void pad_w2(const float* __restrict__ W2, const float* __restrict__ b2,
                       float* __restrict__ Wp, float* __restrict__ bp) {
    int idx = blockIdx.x * blockDim.x + threadIdx.x;
    if (idx < HID_C * PAD_C) {
        int k = idx >> 6, j = idx & 63;
        Wp[idx] = (j < OUT_C) ? W2[k * OUT_C + j] : 0.f;
    }
    if (idx < PAD_C) bp[idx] = (idx < OUT_C) ? b2[idx] : 0.f;
}

// ---------------------------------------------------------------------------
// GEMM2 tiled: h0 = H[M,256] @ Wp[256,64] + bp ; writes fp32 AND bf16 copies
// ---------------------------------------------------------------------------
__global__ __launch_bounds__(256) void gemm2_tiled(const float* __restrict__ H,
                                                   const float* __restrict__ Wp,
                                                   const float* __restrict__ bp,
                                                   float* __restrict__ h0f,
                                                   unsigned short* __restrict__ h0b) {
    __shared__ float As[16][68];
    __shared__ float Bs[16][64];
    const int tid = threadIdx.x;
    const int tx = tid & 15;
    const int ty = tid >> 4;
    const int m0 = blockIdx.x * 64;

    float acc[4][4];
#pragma unroll
    for (int i = 0; i < 4; ++i)
#pragma unroll
        for (int j = 0; j < 4; ++j) acc[i][j] = 0.f;

    const int arow = tid >> 2;
    const int akk  = (tid & 3) << 2;
    const int brow = tid >> 4;
    const int bcol = (tid & 15) << 2;

    for (int k0 = 0; k0 < HID_C; k0 += 16) {
        float4 av = make_float4(0.f, 0.f, 0.f, 0.f);
        int gr = m0 + arow;
        if (gr < N_NODES)
            av = *(const float4*)(H + (size_t)gr * HID_C + k0 + akk);
        As[akk + 0][arow] = av.x;
        As[akk + 1][arow] = av.y;
        As[akk + 2][arow] = av.z;
        As[akk + 3][arow] = av.w;
        float4 bv = *(const float4*)(Wp + (size_t)(k0 + brow) * PAD_C + bcol);
        *(float4*)&Bs[brow][bcol] = bv;
        __syncthreads();

#pragma unroll
        for (int kk = 0; kk < 16; ++kk) {
            float a[4], b[4];
#pragma unroll
            for (int i = 0; i < 4; ++i) a[i] = As[kk][ty * 4 + i];
#pragma unroll
            for (int j = 0; j < 4; ++j) b[j] = Bs[kk][tx * 4 + j];
#pragma unroll
            for (int i = 0; i < 4; ++i)
#pragma unroll
                for (int j = 0; j < 4; ++j) acc[i][j] = fmaf(a[i], b[j], acc[i][j]);
        }
        __syncthreads();
    }

#pragma unroll
    for (int i = 0; i < 4; ++i) {
        int r = m0 + ty * 4 + i;
        if (r >= N_NODES) continue;
#pragma unroll
        for (int j = 0; j < 4; ++j) {
            int c = tx * 4 + j;
            float v = acc[i][j] + bp[c];
            h0f[(size_t)r * PAD_C + c] = v;
            h0b[(size_t)r * PAD_C + c] = f2bf(v);
        }
    }
}

// ---------------------------------------------------------------------------
// CSR build v3 (R7-verified): bucket_scatter -> 98-scan -> fused per-bucket
// hist/scan/scatter. No global histogram, no global fill atomics.
// ---------------------------------------------------------------------------
__global__ __launch_bounds__(256) void bucket_scatter(const int* __restrict__ erow,
                                                      const int* __restrict__ ecol,
                                                      const float* __restrict__ ew,
                                                      int* __restrict__ bfill,
                                                      uint2* __restrict__ buckets) {
    __shared__ int lcnt[NBUCK];
    __shared__ int lbase[NBUCK];
    const int t = threadIdx.x;
    for (int b = t; b < NBUCK; b += 256) lcnt[b] = 0;
    __syncthreads();
    const int e0 = blockIdx.x * PHB_CHUNK;
    const int e1 = min(e0 + PHB_CHUNK, N_EDGES);
    for (int e = e0 + t; e < e1; e += 256)
        atomicAdd(&lcnt[erow[e] >> BSHIFT], 1);
    __syncthreads();
    for (int b = t; b < NBUCK; b += 256) {
        lbase[b] = atomicAdd(&bfill[b], lcnt[b]);
        lcnt[b] = 0;
    }
    __syncthreads();
    for (int e = e0 + t; e < e1; e += 256) {
        int r = erow[e];
        int b = r >> BSHIFT;
        int o = atomicAdd(&lcnt[b], 1);
        int idx = lbase[b] + o;
        if (idx < BCAP) {   // BCAP = mean + 32 sigma: always true
            unsigned packed = ((unsigned)(r - (b << BSHIFT)) << 17) | (unsigned)ecol[e];
            buckets[(size_t)b * BCAP + idx] = make_uint2(packed, __float_as_uint(ew[e]));
        }
    }
}

__global__ __launch_bounds__(128) void bucket_scan(const int* __restrict__ bfill,
                                                   int* __restrict__ bbase,
                                                   int* __restrict__ rowptr) {
    __shared__ int sd[128];
    int t = threadIdx.x;
    int v = (t < NBUCK) ? min(bfill[t], BCAP) : 0;
    sd[t] = v;
    __syncthreads();
    for (int off = 1; off < 128; off <<= 1) {
        int x = (t >= off) ? sd[t - off] : 0;
        __syncthreads();
        sd[t] += x;
        __syncthreads();
    }
    if (t < NBUCK) bbase[t] = sd[t] - v;
    if (t == NBUCK - 1) {
        bbase[NBUCK] = sd[t];
        rowptr[N_NODES] = sd[t];
    }
}

__global__ __launch_bounds__(256) void bucket_csr(const uint2* __restrict__ buckets,
                                                  const int* __restrict__ bfill,
                                                  const int* __restrict__ bbase,
                                                  int* __restrict__ rowptr,
                                                  uint2* __restrict__ edges) {
    __shared__ int hist[512];
    __shared__ int excl[512];
    __shared__ int psum[256];
    const int b = blockIdx.x;
    const int t = threadIdx.x;
    const int n = min(bfill[b], BCAP);
    const uint2* bk = buckets + (size_t)b * BCAP;

    hist[t] = 0; hist[t + 256] = 0;
    __syncthreads();
    for (int i = t; i < n; i += 256)
        atomicAdd(&hist[bk[i].x >> 17], 1);
    __syncthreads();
    int a0 = hist[2 * t], a1 = hist[2 * t + 1];
    psum[t] = a0 + a1;
    __syncthreads();
    for (int off = 1; off < 256; off <<= 1) {
        int x = (t >= off) ? psum[t - off] : 0;
        __syncthreads();
        psum[t] += x;
        __syncthreads();
    }
    int pe = psum[t] - (a0 + a1);
    excl[2 * t] = pe;
    excl[2 * t + 1] = pe + a0;
    __syncthreads();
    const int base = bbase[b];
#pragma unroll
    for (int k = 0; k < 2; ++k) {
        int lr = t + k * 256;
        int r = (b << BSHIFT) + lr;
        if (r < N_NODES) rowptr[r] = base + excl[lr];
    }
    hist[t] = 0; hist[t + 256] = 0;
    __syncthreads();
    for (int i = t; i < n; i += 256) {
        uint2 ed = bk[i];
        int lr = ed.x >> 17;
        int pos = base + excl[lr] + atomicAdd(&hist[lr], 1);
        edges[pos] = make_uint2(ed.x & 0x1FFFFu, ed.y);
    }
}

// ---------------------------------------------------------------------------
// Propagation (R6-verified prop8): 8 lanes x 16 B cover one 128 B row -> one
// gather serves 8 edges; x2 unroll; xor(8/16/32) all-reduce; LAST layer
// fuses log_softmax and writes d_out directly.
// ---------------------------------------------------------------------------
template <bool LAST>
__global__ __launch_bounds__(256) void prop8(const int* __restrict__ rowptr,
                                             const uint2* __restrict__ edges,
                                             const unsigned short* __restrict__ hin,
                                             const float* __restrict__ h0f,
                                             unsigned short* __restrict__ hout_b,
                                             float* __restrict__ out_f) {
    int wid = (blockIdx.x * blockDim.x + threadIdx.x) >> 6;
    if (wid >= N_NODES) return;
    int lane = threadIdx.x & 63;
    int slot = lane >> 3;
    int lc   = lane & 7;
    int s = rowptr[wid], e = rowptr[wid + 1];

    float acc0[8], acc1[8];
#pragma unroll
    for (int k = 0; k < 8; ++k) { acc0[k] = 0.f; acc1[k] = 0.f; }

    int i = s;
    for (; i + 16 <= e; i += 16) {
        uint2 cw0 = edges[i + slot];
        uint2 cw1 = edges[i + 8 + slot];
        uint4 hv0 = *(const uint4*)((const char*)hin + ((size_t)cw0.x << 7) + lc * 16);
        uint4 hv1 = *(const uint4*)((const char*)hin + ((size_t)cw1.x << 7) + lc * 16);
        float w0 = __uint_as_float(cw0.y);
        float w1 = __uint_as_float(cw1.y);
        acc0[0] = fmaf(w0, __uint_as_float(hv0.x << 16),         acc0[0]);
        acc0[1] = fmaf(w0, __uint_as_float(hv0.x & 0xffff0000u), acc0[1]);
        acc0[2] = fmaf(w0, __uint_as_float(hv0.y << 16),         acc0[2]);
        acc0[3] = fmaf(w0, __uint_as_float(hv0.y & 0xffff0000u), acc0[3]);
        acc0[4] = fmaf(w0, __uint_as_float(hv0.z << 16),         acc0[4]);
        acc0[5] = fmaf(w0, __uint_as_float(hv0.z & 0xffff0000u), acc0[5]);
        acc0[6] = fmaf(w0, __uint_as_float(hv0.w << 16),         acc0[6]);
        acc0[7] = fmaf(w0, __uint_as_float(hv0.w & 0xffff0000u), acc0[7]);
        acc1[0] = fmaf(w1, __uint_as_float(hv1.x << 16),         acc1[0]);
        acc1[1] = fmaf(w1, __uint_as_float(hv1.x & 0xffff0000u), acc1[1]);
        acc1[2] = fmaf(w1, __uint_as_float(hv1.y << 16),         acc1[2]);
        acc1[3] = fmaf(w1, __uint_as_float(hv1.y & 0xffff0000u), acc1[3]);
        acc1[4] = fmaf(w1, __uint_as_float(hv1.z << 16),         acc1[4]);
        acc1[5] = fmaf(w1, __uint_as_float(hv1.z & 0xffff0000u), acc1[5]);
        acc1[6] = fmaf(w1, __uint_as_float(hv1.w << 16),         acc1[6]);
        acc1[7] = fmaf(w1, __uint_as_float(hv1.w & 0xffff0000u), acc1[7]);
    }
    for (; i < e; i += 8) {
        int idx = i + slot;
        uint2 cw = (idx < e) ? edges[idx] : make_uint2(0u, 0u);
        float w  = (idx < e) ? __uint_as_float(cw.y) : 0.f;
        uint4 hv = *(const uint4*)((const char*)hin + ((size_t)cw.x << 7) + lc * 16);
        acc0[0] = fmaf(w, __uint_as_float(hv.x << 16),         acc0[0]);
        acc0[1] = fmaf(w, __uint_as_float(hv.x & 0xffff0000u), acc0[1]);
        acc0[2] = fmaf(w, __uint_as_float(hv.y << 16),         acc0[2]);
        acc0[3] = fmaf(w, __uint_as_float(hv.y & 0xffff0000u), acc0[3]);
        acc0[4] = fmaf(w, __uint_as_float(hv.z << 16),         acc0[4]);
        acc0[5] = fmaf(w, __uint_as_float(hv.z & 0xffff0000u), acc0[5]);
        acc0[6] = fmaf(w, __uint_as_float(hv.w << 16),         acc0[6]);
        acc0[7] = fmaf(w, __uint_as_float(hv.w & 0xffff0000u), acc0[7]);
    }

    float r[8];
#pragma unroll
    for (int k = 0; k < 8; ++k) {
        float v = acc0[k] + acc1[k];
        v += __shfl_xor(v, 8, 64);
        v += __shfl_xor(v, 16, 64);
        v += __shfl_xor(v, 32, 64);
        r[k] = v;
    }

    size_t off = (size_t)wid * PAD_C + lc * 8;
    float4 h0a = *(const float4*)(h0f + off);
    float4 h0b4 = *(const float4*)(h0f + off + 4);
    r[0] = 0.9f * r[0] + 0.1f * h0a.x;  r[1] = 0.9f * r[1] + 0.1f * h0a.y;
    r[2] = 0.9f * r[2] + 0.1f * h0a.z;  r[3] = 0.9f * r[3] + 0.1f * h0a.w;
    r[4] = 0.9f * r[4] + 0.1f * h0b4.x; r[5] = 0.9f * r[5] + 0.1f * h0b4.y;
    r[6] = 0.9f * r[6] + 0.1f * h0b4.z; r[7] = 0.9f * r[7] + 0.1f * h0b4.w;

    if (!LAST) {
        if (slot == 0) {
            uint4 u;
            u.x = ((unsigned)f2bf(r[1]) << 16) | f2bf(r[0]);
            u.y = ((unsigned)f2bf(r[3]) << 16) | f2bf(r[2]);
            u.z = ((unsigned)f2bf(r[5]) << 16) | f2bf(r[4]);
            u.w = ((unsigned)f2bf(r[7]) << 16) | f2bf(r[6]);
            *(uint4*)((char*)hout_b + ((size_t)wid << 7) + lc * 16) = u;
        }
    } else {
        int ch0 = lc * 8;
        float m = -INFINITY;
#pragma unroll
        for (int k = 0; k < 8; ++k) if (ch0 + k < OUT_C) m = fmaxf(m, r[k]);
        m = fmaxf(m, __shfl_xor(m, 1, 64));
        m = fmaxf(m, __shfl_xor(m, 2, 64));
        m = fmaxf(m, __shfl_xor(m, 4, 64));
        float ss = 0.f;
#pragma unroll
        for (int k = 0; k < 8; ++k) if (ch0 + k < OUT_C) ss += __expf(r[k] - m);
        ss += __shfl_xor(ss, 1, 64);
        ss += __shfl_xor(ss, 2, 64);
        ss += __shfl_xor(ss, 4, 64);
        float lse = __logf(ss);
        if (slot == 0) {
#pragma unroll
            for (int k = 0; k < 8; ++k)
                if (ch0 + k < OUT_C)
                    out_f[(size_t)wid * OUT_C + ch0 + k] = (r[k] - m) - lse;
        }
    }
}

// ---------------------------------------------------------------------------
extern "C" void kernel_launch(void* const* d_in, const int* in_sizes, int n_in,
                              void* d_out, int out_size, void* d_ws, size_t ws_size,
                              hipStream_t stream) {
    const float* x    = (const float*)d_in[0];
    const int*   erow = (const int*)d_in[1];
    const int*   ecol = (const int*)d_in[2];
    const float* ew   = (const float*)d_in[3];
    const float* W1   = (const float*)d_in[4];
    const float* b1   = (const float*)d_in[5];
    const float* W2   = (const float*)d_in[6];
    const float* b2   = (const float*)d_in[7];
    float* out = (float*)d_out;

    char* p = (char*)d_ws;
    auto alloc = [&](size_t bytes) {
        char* r = p;
        p += (bytes + 255) & ~(size_t)255;
        return r;
    };
    char*  h_hid_raw = alloc((size_t)N_NODES * HID_C * 4);        // 51.2 MB region
    float* h_hid  = (float*)h_hid_raw;
    float* h0f    = (float*)alloc((size_t)N_NODES * PAD_C * 4);   // 12.8 MB
    unsigned short* h0b = (unsigned short*)alloc((size_t)N_NODES * PAD_C * 2); // 6.4 MB
    uint2* edges  = (uint2*)alloc((size_t)N_EDGES * 8);           // 12.8 MB packed CSR
    int*   rowptr = (int*)alloc((size_t)(N_NODES + 1) * 4);
    int*   bfill  = (int*)alloc((size_t)NBUCK * 4);
    int*   bbase  = (int*)alloc((size_t)(NBUCK + 1) * 4);
    float* Wp     = (float*)alloc((size_t)HID_C * PAD_C * 4);
    float* bp     = (float*)alloc((size_t)PAD_C * 4);
    unsigned short* Wt = (unsigned short*)alloc((size_t)HID_C * IN_C * 2);
    // --- aliases onto h_hid region (sequential lifetimes, stream-ordered):
    uint2* buckets = (uint2*)h_hid_raw;                                       // 16.1 MB (CSR build)
    unsigned short* ha = (unsigned short*)h_hid_raw;                          // 6.4 MB (prop)
    unsigned short* hb = (unsigned short*)(h_hid_raw + (size_t)N_NODES * PAD_C * 2); // 6.4 MB

    hipMemsetAsync(bfill, 0, (size_t)NBUCK * 4, stream);

    // CSR build (v3)
    bucket_scatter<<<PHB_BLOCKS, 256, 0, stream>>>(erow, ecol, ew, bfill, buckets);
    bucket_scan<<<1, 128, 0, stream>>>(bfill, bbase, rowptr);
    bucket_csr<<<NBUCK, 256, 0, stream>>>(buckets, bfill, bbase, rowptr, edges);

    // MLP
    transpose_w1<<<dim3(IN_C / 32, HID_C / 32), 256, 0, stream>>>(W1, Wt);
    gemm1_mfma<<<dim3((N_NODES + 63) / 64), 256, 0, stream>>>(x, Wt, b1, h_hid);
    pad_w2<<<(HID_C * PAD_C + 255) / 256, 256, 0, stream>>>(W2, b2, Wp, bp);
    gemm2_tiled<<<(N_NODES + 63) / 64, 256, 0, stream>>>(h_hid, Wp, bp, h0f, h0b);

    // Propagation x10 (bf16 ping-pong; last layer fuses log_softmax -> out)
    const int prop_blocks = (N_NODES * 64 + 255) / 256;
    const unsigned short* cur = h0b;
    unsigned short* nxt = ha;
    for (int l = 0; l < NUM_LAYERS - 1; ++l) {
        prop8<false><<<prop_blocks, 256, 0, stream>>>(rowptr, edges, cur, h0f,
                                                      nxt, nullptr);
        const unsigned short* t = nxt;
        nxt = (nxt == ha) ? hb : ha;
        cur = t;
    }
    prop8<true><<<prop_blocks, 256, 0, stream>>>(rowptr, edges, cur, h0f,
                                                 nullptr, out);
}

// Round 2
// 631.799 us; speedup vs baseline: 1.0879x; 1.0221x over previous
//
#include <hip/hip_runtime.h>
#include <cstddef>
#include <cstdint>
#include <math.h>

#define N_NODES 50000
#define N_EDGES 1600000
#define IN_C 512
#define HID_C 256
#define OUT_C 50
#define PAD_C 64
#define NUM_LAYERS 10
#define NBUCK 98          // ceil(50000/512) row-buckets
#define BSHIFT 9          // 512 rows per bucket
#define BCAP 20480        // mean 16327 + 32 sigma — overflow unreachable
#define PHB_CHUNK 8192    // edges per block in bucket_scatter
#define PHB_BLOCKS 196    // ceil(N_EDGES / PHB_CHUNK)

typedef __attribute__((ext_vector_type(8))) short short8;    // 8 bf16 (4 VGPRs)
typedef __attribute__((ext_vector_type(4))) float floatx4;   // MFMA C/D frag

__device__ inline unsigned short f2bf(float f) {             // RNE fp32->bf16
    unsigned int u = __float_as_uint(f);
    u += 0x7fffu + ((u >> 16) & 1u);
    return (unsigned short)(u >> 16);
}

// async 16B global->LDS (LDS dest is wave-uniform base + lane*16: all dests
// below are linear in tid, verified)
#define ASYNC16(g, l)                                                     \
    __builtin_amdgcn_global_load_lds(                                     \
        (const __attribute__((address_space(1))) void*)(g),               \
        (__attribute__((address_space(3))) void*)(l), 16, 0, 0)

#define WAITCNT6() asm volatile("s_waitcnt vmcnt(6)" ::: "memory")
#define WAITCNT0() asm volatile("s_waitcnt vmcnt(0)" ::: "memory")
#define SBAR()     __builtin_amdgcn_s_barrier()
#define SFENCE()   __builtin_amdgcn_sched_barrier(0)

// ---------------------------------------------------------------------------
// W1 [512,256] fp32  ->  Wt [256,512] bf16   (LDS-tiled transpose)
// ---------------------------------------------------------------------------
__global__ __launch_bounds__(256) void transpose_w1(const float* __restrict__ W1,
                                                    unsigned short* __restrict__ Wt) {
    __shared__ float tile[32][33];
    int bx = blockIdx.x;               // k-tile (16)
    int by = blockIdx.y;               // n-tile (8)
    int tx = threadIdx.x & 31, ty = threadIdx.x >> 5;   // 32 x 8
#pragma unroll
    for (int i = 0; i < 32; i += 8)
        tile[ty + i][tx] = W1[(bx * 32 + ty + i) * HID_C + by * 32 + tx];
    __syncthreads();
#pragma unroll
    for (int i = 0; i < 32; i += 8)
        Wt[(size_t)(by * 32 + ty + i) * IN_C + bx * 32 + tx] = f2bf(tile[tx][ty + i]);
}

// ---------------------------------------------------------------------------
// pad_w2 v2: W2 [256,50] fp32 -> Wpt [64,256] bf16 TRANSPOSED (MFMA B-frag
// layout: row n = output col, 256 k contiguous), b2 -> bp[64] fp32.
// ---------------------------------------------------------------------------
__global__ void pad_w2(const float* __restrict__ W2, const float* __restrict__ b2,
                       unsigned short* __restrict__ Wpt, float* __restrict__ bp) {
    int idx = blockIdx.x * blockDim.x + threadIdx.x;
    if (idx < PAD_C * HID_C) {
        int n = idx >> 8, k = idx & 255;
        float v = (n < OUT_C) ? W2[k * OUT_C + n] : 0.f;
        Wpt[idx] = f2bf(v);
    }
    if (idx < PAD_C) bp[idx] = (idx < OUT_C) ? b2[idx] : 0.f;
}

// ---------------------------------------------------------------------------
// GEMM1+GEMM2 fused: h = relu(x[64,512] @ W1 + b1) (tile is FULL HID_C wide,
// so each block owns complete h rows) -> stage h to LDS bf16 -> h0 = h @ W2
// + b2 via 128 more MFMA -> write h0f/h0b directly. h_hid never touches HBM.
//
// Main-loop changes vs R1:
//  * counted-vmcnt pipeline (T4): raw s_barrier + s_waitcnt vmcnt(6); the
//    next stage's 6 loads stay in flight across compute, never drained to 0.
//  * B staged CHUNK-MAJOR (slot = chunk*256 + n): LDS dest still linear in
//    tid (global_load_lds requirement) but the ds_read_b128 of 16 consecutive
//    n's now hits 16 consecutive 16B slots -> conflict-free (was 8-way).
//  * A unchanged: row-major + XOR-swizzled SOURCE chunk (2-way max, free).
// ---------------------------------------------------------------------------
__global__ __launch_bounds__(256) void gemm1_fused(const float* __restrict__ A,
                                                   const unsigned short* __restrict__ Wt,
                                                   const float* __restrict__ b1,
                                                   const unsigned short* __restrict__ Wpt,
                                                   const float* __restrict__ bp,
                                                   float* __restrict__ h0f,
                                                   unsigned short* __restrict__ h0b) {
    __shared__ __align__(16) char smem[49152];
    float*          As0 = (float*)smem;                         // 8 KB
    float*          As1 = (float*)(smem + 8192);                // 8 KB
    unsigned short* Bs0 = (unsigned short*)(smem + 16384);      // 16 KB
    unsigned short* Bs1 = (unsigned short*)(smem + 32768);      // 16 KB
    unsigned short* Hs  = (unsigned short*)smem;                // [64][264] bf16, 33 KB (reused)
    const int HS_LD = 264;   // 528 B row stride = 33*16 B: aligned, conflict-free reads

    const int tid  = threadIdx.x;
    const int wave = tid >> 6, lane = tid & 63;
    const int quad = lane >> 4, l16 = lane & 15;
    const int m0 = blockIdx.x * 64;
    const int wm = (wave >> 1) * 32;               // row offset of this wave
    const int wn = (wave & 1) * 128;               // col offset of this wave

    floatx4 acc[2][8];
#pragma unroll
    for (int i = 0; i < 2; ++i)
#pragma unroll
        for (int j = 0; j < 8; ++j) acc[i][j] = (floatx4){0.f, 0.f, 0.f, 0.f};

    // one BK=32 slab: A 64x32 fp32 (2 loads/thr) + B 256x32 bf16 (4 loads/thr)
    // = exactly 6 VMEM instructions per wave per stage (vmcnt unit).
    auto stage = [&](float* As_, unsigned short* Bs_, int k0) {
#pragma unroll
        for (int j = 0; j < 2; ++j) {
            int slot = tid + j * 256;              // [0,512): r = slot>>3, c = slot&7
            int r = slot >> 3, c = slot & 7;
            int gr = m0 + r;
            if (gr >= N_NODES) gr = N_NODES - 1;   // clamp: finite garbage, masked later
            const float* src = A + (size_t)gr * IN_C + k0 + ((c ^ (r & 7)) << 2);
            ASYNC16(src, As_ + (slot << 2));
        }
#pragma unroll
        for (int j = 0; j < 4; ++j) {
            // chunk-major: slot = j*256 + tid -> LDS shorts offset slot*8
            const unsigned short* src = Wt + (size_t)tid * IN_C + k0 + (j << 3);
            ASYNC16(src, Bs_ + (j << 11) + (tid << 3));
        }
    };

    auto compute = [&](const float* As_, const unsigned short* Bs_) {
        short8 bfr[8], afr[2];
#pragma unroll
        for (int nt = 0; nt < 8; ++nt) {
            int n = wn + nt * 16 + l16;
            bfr[nt] = *(const short8*)&Bs_[(quad << 11) + (n << 3)];   // (quad*256+n)*8
        }
#pragma unroll
        for (int mt = 0; mt < 2; ++mt) {
            int r  = wm + mt * 16 + l16;
            int rx = r & 7;
            float4 lo = *(const float4*)&As_[(r << 5) + (((2 * quad)     ^ rx) << 2)];
            float4 hi = *(const float4*)&As_[(r << 5) + (((2 * quad + 1) ^ rx) << 2)];
            short8 a;
            a[0] = (short)f2bf(lo.x); a[1] = (short)f2bf(lo.y);
            a[2] = (short)f2bf(lo.z); a[3] = (short)f2bf(lo.w);
            a[4] = (short)f2bf(hi.x); a[5] = (short)f2bf(hi.y);
            a[6] = (short)f2bf(hi.z); a[7] = (short)f2bf(hi.w);
            afr[mt] = a;
        }
#pragma unroll
        for (int mt = 0; mt < 2; ++mt)
#pragma unroll
            for (int nt = 0; nt < 8; ++nt)
                acc[mt][nt] = __builtin_amdgcn_mfma_f32_16x16x32_bf16(afr[mt], bfr[nt],
                                                                      acc[mt][nt], 0, 0, 0);
    };

    // --- pipelined main loop: 16 K-steps, 2 buffers, counted vmcnt ---------
    stage(As0, Bs0, 0);
    stage(As1, Bs1, 32);
    WAITCNT6(); SFENCE(); SBAR(); SFENCE();        // buf0 landed for all waves
    for (int kk = 0; kk < 7; ++kk) {
        compute(As0, Bs0);
        SFENCE(); SBAR(); SFENCE();                // all waves done reading buf0
        stage(As0, Bs0, (2 * kk + 2) * 32);        // overwrite buf0 (async)
        WAITCNT6(); SFENCE(); SBAR(); SFENCE();    // buf1 landed (6 newest = buf0's)
        compute(As1, Bs1);
        SFENCE(); SBAR(); SFENCE();
        stage(As1, Bs1, (2 * kk + 3) * 32);
        WAITCNT6(); SFENCE(); SBAR(); SFENCE();
    }
    compute(As0, Bs0);                             // ks = 14
    SFENCE(); SBAR(); SFENCE();
    WAITCNT0(); SFENCE(); SBAR(); SFENCE();        // drain ks=15's loads
    compute(As1, Bs1);                             // ks = 15
    __syncthreads();                               // before Hs overlays As/Bs

    // --- stage relu(h + b1) to LDS bf16 (row = quad*4+r, col = l16 map) ----
#pragma unroll
    for (int nt = 0; nt < 8; ++nt) {
        int n = wn + nt * 16 + l16;
        float bn = b1[n];
#pragma unroll
        for (int mt = 0; mt < 2; ++mt)
#pragma unroll
            for (int r = 0; r < 4; ++r) {
                float v = acc[mt][nt][r] + bn;
                v = v > 0.f ? v : 0.f;
                Hs[(wm + mt * 16 + quad * 4 + r) * HS_LD + n] = f2bf(v);
            }
    }
    __syncthreads();

    // --- fused GEMM2: h0[64,64] = Hs[64,256] @ Wpt^T + bp ------------------
    // wave w owns rows w*16..w*16+16; B-frags streamed from global Wpt (L2-hot)
    floatx4 acc2[4];
#pragma unroll
    for (int nt = 0; nt < 4; ++nt) acc2[nt] = (floatx4){0.f, 0.f, 0.f, 0.f};
    const int hrow = (wave << 4) + l16;
#pragma unroll
    for (int k2 = 0; k2 < 8; ++k2) {
        short8 haf = *(const short8*)&Hs[hrow * HS_LD + (k2 << 5) + (quad << 3)];
#pragma unroll
        for (int nt = 0; nt < 4; ++nt) {
            short8 bf = *(const short8*)&Wpt[(size_t)((nt << 4) + l16) * HID_C + (k2 << 5) + (quad << 3)];
            acc2[nt] = __builtin_amdgcn_mfma_f32_16x16x32_bf16(haf, bf, acc2[nt], 0, 0, 0);
        }
    }
#pragma unroll
    for (int nt = 0; nt < 4; ++nt) {
        int c = (nt << 4) + l16;
        float bn = bp[c];
#pragma unroll
        for (int r = 0; r < 4; ++r) {
            int row = m0 + (wave << 4) + (quad << 2) + r;
            if (row < N_NODES) {
                float v = acc2[nt][r] + bn;
                h0f[(size_t)row * PAD_C + c] = v;
                h0b[(size_t)row * PAD_C + c] = f2bf(v);
            }
        }
    }
}

// ---------------------------------------------------------------------------
// CSR build v3 (R7-verified): bucket_scatter -> 98-scan -> fused per-bucket
// hist/scan/scatter. No global histogram, no global fill atomics.
// ---------------------------------------------------------------------------
__global__ __launch_bounds__(256) void bucket_scatter(const int* __restrict__ erow,
                                                      const int* __restrict__ ecol,
                                                      const float* __restrict__ ew,
                                                      int* __restrict__ bfill,
                                                      uint2* __restrict__ buckets) {
    __shared__ int lcnt[NBUCK];
    __shared__ int lbase[NBUCK];
    const int t = threadIdx.x;
    for (int b = t; b < NBUCK; b += 256) lcnt[b] = 0;
    __syncthreads();
    const int e0 = blockIdx.x * PHB_CHUNK;
    const int e1 = min(e0 + PHB_CHUNK, N_EDGES);
    for (int e = e0 + t; e < e1; e += 256)
        atomicAdd(&lcnt[erow[e] >> BSHIFT], 1);
    __syncthreads();
    for (int b = t; b < NBUCK; b += 256) {
        lbase[b] = atomicAdd(&bfill[b], lcnt[b]);
        lcnt[b] = 0;
    }
    __syncthreads();
    for (int e = e0 + t; e < e1; e += 256) {
        int r = erow[e];
        int b = r >> BSHIFT;
        int o = atomicAdd(&lcnt[b], 1);
        int idx = lbase[b] + o;
        if (idx < BCAP) {   // BCAP = mean + 32 sigma: always true
            unsigned packed = ((unsigned)(r - (b << BSHIFT)) << 17) | (unsigned)ecol[e];
            buckets[(size_t)b * BCAP + idx] = make_uint2(packed, __float_as_uint(ew[e]));
        }
    }
}

__global__ __launch_bounds__(128) void bucket_scan(const int* __restrict__ bfill,
                                                   int* __restrict__ bbase,
                                                   int* __restrict__ rowptr) {
    __shared__ int sd[128];
    int t = threadIdx.x;
    int v = (t < NBUCK) ? min(bfill[t], BCAP) : 0;
    sd[t] = v;
    __syncthreads();
    for (int off = 1; off < 128; off <<= 1) {
        int x = (t >= off) ? sd[t - off] : 0;
        __syncthreads();
        sd[t] += x;
        __syncthreads();
    }
    if (t < NBUCK) bbase[t] = sd[t] - v;
    if (t == NBUCK - 1) {
        bbase[NBUCK] = sd[t];
        rowptr[N_NODES] = sd[t];
    }
}

__global__ __launch_bounds__(256) void bucket_csr(const uint2* __restrict__ buckets,
                                                  const int* __restrict__ bfill,
                                                  const int* __restrict__ bbase,
                                                  int* __restrict__ rowptr,
                                                  uint2* __restrict__ edges) {
    __shared__ int hist[512];
    __shared__ int excl[512];
    __shared__ int psum[256];
    const int b = blockIdx.x;
    const int t = threadIdx.x;
    const int n = min(bfill[b], BCAP);
    const uint2* bk = buckets + (size_t)b * BCAP;

    hist[t] = 0; hist[t + 256] = 0;
    __syncthreads();
    for (int i = t; i < n; i += 256)
        atomicAdd(&hist[bk[i].x >> 17], 1);
    __syncthreads();
    int a0 = hist[2 * t], a1 = hist[2 * t + 1];
    psum[t] = a0 + a1;
    __syncthreads();
    for (int off = 1; off < 256; off <<= 1) {
        int x = (t >= off) ? psum[t - off] : 0;
        __syncthreads();
        psum[t] += x;
        __syncthreads();
    }
    int pe = psum[t] - (a0 + a1);
    excl[2 * t] = pe;
    excl[2 * t + 1] = pe + a0;
    __syncthreads();
    const int base = bbase[b];
#pragma unroll
    for (int k = 0; k < 2; ++k) {
        int lr = t + k * 256;
        int r = (b << BSHIFT) + lr;
        if (r < N_NODES) rowptr[r] = base + excl[lr];
    }
    hist[t] = 0; hist[t + 256] = 0;
    __syncthreads();
    for (int i = t; i < n; i += 256) {
        uint2 ed = bk[i];
        int lr = ed.x >> 17;
        int pos = base + excl[lr] + atomicAdd(&hist[lr], 1);
        edges[pos] = make_uint2(ed.x & 0x1FFFFu, ed.y);
    }
}

// ---------------------------------------------------------------------------
// Propagation (R6-verified prop8): 8 lanes x 16 B cover one 128 B row -> one
// gather serves 8 edges; x2 unroll; xor(8/16/32) all-reduce; LAST layer
// fuses log_softmax and writes d_out directly.
// ---------------------------------------------------------------------------
template <bool LAST>
__global__ __launch_bounds__(256) void prop8(const int* __restrict__ rowptr,
                                             const uint2* __restrict__ edges,
                                             const unsigned short* __restrict__ hin,
                                             const float* __restrict__ h0f,
                                             unsigned short* __restrict__ hout_b,
                                             float* __restrict__ out_f) {
    int wid = (blockIdx.x * blockDim.x + threadIdx.x) >> 6;
    if (wid >= N_NODES) return;
    int lane = threadIdx.x & 63;
    int slot = lane >> 3;
    int lc   = lane & 7;
    int s = rowptr[wid], e = rowptr[wid + 1];

    float acc0[8], acc1[8];
#pragma unroll
    for (int k = 0; k < 8; ++k) { acc0[k] = 0.f; acc1[k] = 0.f; }

    int i = s;
    for (; i + 16 <= e; i += 16) {
        uint2 cw0 = edges[i + slot];
        uint2 cw1 = edges[i + 8 + slot];
        uint4 hv0 = *(const uint4*)((const char*)hin + ((size_t)cw0.x << 7) + lc * 16);
        uint4 hv1 = *(const uint4*)((const char*)hin + ((size_t)cw1.x << 7) + lc * 16);
        float w0 = __uint_as_float(cw0.y);
        float w1 = __uint_as_float(cw1.y);
        acc0[0] = fmaf(w0, __uint_as_float(hv0.x << 16),         acc0[0]);
        acc0[1] = fmaf(w0, __uint_as_float(hv0.x & 0xffff0000u), acc0[1]);
        acc0[2] = fmaf(w0, __uint_as_float(hv0.y << 16),         acc0[2]);
        acc0[3] = fmaf(w0, __uint_as_float(hv0.y & 0xffff0000u), acc0[3]);
        acc0[4] = fmaf(w0, __uint_as_float(hv0.z << 16),         acc0[4]);
        acc0[5] = fmaf(w0, __uint_as_float(hv0.z & 0xffff0000u), acc0[5]);
        acc0[6] = fmaf(w0, __uint_as_float(hv0.w << 16),         acc0[6]);
        acc0[7] = fmaf(w0, __uint_as_float(hv0.w & 0xffff0000u), acc0[7]);
        acc1[0] = fmaf(w1, __uint_as_float(hv1.x << 16),         acc1[0]);
        acc1[1] = fmaf(w1, __uint_as_float(hv1.x & 0xffff0000u), acc1[1]);
        acc1[2] = fmaf(w1, __uint_as_float(hv1.y << 16),         acc1[2]);
        acc1[3] = fmaf(w1, __uint_as_float(hv1.y & 0xffff0000u), acc1[3]);
        acc1[4] = fmaf(w1, __uint_as_float(hv1.z << 16),         acc1[4]);
        acc1[5] = fmaf(w1, __uint_as_float(hv1.z & 0xffff0000u), acc1[5]);
        acc1[6] = fmaf(w1, __uint_as_float(hv1.w << 16),         acc1[6]);
        acc1[7] = fmaf(w1, __uint_as_float(hv1.w & 0xffff0000u), acc1[7]);
    }
    for (; i < e; i += 8) {
        int idx = i + slot;
        uint2 cw = (idx < e) ? edges[idx] : make_uint2(0u, 0u);
        float w  = (idx < e) ? __uint_as_float(cw.y) : 0.f;
        uint4 hv = *(const uint4*)((const char*)hin + ((size_t)cw.x << 7) + lc * 16);
        acc0[0] = fmaf(w, __uint_as_float(hv.x << 16),         acc0[0]);
        acc0[1] = fmaf(w, __uint_as_float(hv.x & 0xffff0000u), acc0[1]);
        acc0[2] = fmaf(w, __uint_as_float(hv.y << 16),         acc0[2]);
        acc0[3] = fmaf(w, __uint_as_float(hv.y & 0xffff0000u), acc0[3]);
        acc0[4] = fmaf(w, __uint_as_float(hv.z << 16),         acc0[4]);
        acc0[5] = fmaf(w, __uint_as_float(hv.z & 0xffff0000u), acc0[5]);
        acc0[6] = fmaf(w, __uint_as_float(hv.w << 16),         acc0[6]);
        acc0[7] = fmaf(w, __uint_as_float(hv.w & 0xffff0000u), acc0[7]);
    }

    float r[8];
#pragma unroll
    for (int k = 0; k < 8; ++k) {
        float v = acc0[k] + acc1[k];
        v += __shfl_xor(v, 8, 64);
        v += __shfl_xor(v, 16, 64);
        v += __shfl_xor(v, 32, 64);
        r[k] = v;
    }

    size_t off = (size_t)wid * PAD_C + lc * 8;
    float4 h0a = *(const float4*)(h0f + off);
    float4 h0b4 = *(const float4*)(h0f + off + 4);
    r[0] = 0.9f * r[0] + 0.1f * h0a.x;  r[1] = 0.9f * r[1] + 0.1f * h0a.y;
    r[2] = 0.9f * r[2] + 0.1f * h0a.z;  r[3] = 0.9f * r[3] + 0.1f * h0a.w;
    r[4] = 0.9f * r[4] + 0.1f * h0b4.x; r[5] = 0.9f * r[5] + 0.1f * h0b4.y;
    r[6] = 0.9f * r[6] + 0.1f * h0b4.z; r[7] = 0.9f * r[7] + 0.1f * h0b4.w;

    if (!LAST) {
        if (slot == 0) {
            uint4 u;
            u.x = ((unsigned)f2bf(r[1]) << 16) | f2bf(r[0]);
            u.y = ((unsigned)f2bf(r[3]) << 16) | f2bf(r[2]);
            u.z = ((unsigned)f2bf(r[5]) << 16) | f2bf(r[4]);
            u.w = ((unsigned)f2bf(r[7]) << 16) | f2bf(r[6]);
            *(uint4*)((char*)hout_b + ((size_t)wid << 7) + lc * 16) = u;
        }
    } else {
        int ch0 = lc * 8;
        float m = -INFINITY;
#pragma unroll
        for (int k = 0; k < 8; ++k) if (ch0 + k < OUT_C) m = fmaxf(m, r[k]);
        m = fmaxf(m, __shfl_xor(m, 1, 64));
        m = fmaxf(m, __shfl_xor(m, 2, 64));
        m = fmaxf(m, __shfl_xor(m, 4, 64));
        float ss = 0.f;
#pragma unroll
        for (int k = 0; k < 8; ++k) if (ch0 + k < OUT_C) ss += __expf(r[k] - m);
        ss += __shfl_xor(ss, 1, 64);
        ss += __shfl_xor(ss, 2, 64);
        ss += __shfl_xor(ss, 4, 64);
        float lse = __logf(ss);
        if (slot == 0) {
#pragma unroll
            for (int k = 0; k < 8; ++k)
                if (ch0 + k < OUT_C)
                    out_f[(size_t)wid * OUT_C + ch0 + k] = (r[k] - m) - lse;
        }
    }
}

// ---------------------------------------------------------------------------
extern "C" void kernel_launch(void* const* d_in, const int* in_sizes, int n_in,
                              void* d_out, int out_size, void* d_ws, size_t ws_size,
                              hipStream_t stream) {
    const float* x    = (const float*)d_in[0];
    const int*   erow = (const int*)d_in[1];
    const int*   ecol = (const int*)d_in[2];
    const float* ew   = (const float*)d_in[3];
    const float* W1   = (const float*)d_in[4];
    const float* b1   = (const float*)d_in[5];
    const float* W2   = (const float*)d_in[6];
    const float* b2   = (const float*)d_in[7];
    float* out = (float*)d_out;

    char* p = (char*)d_ws;
    auto alloc = [&](size_t bytes) {
        char* r = p;
        p += (bytes + 255) & ~(size_t)255;
        return r;
    };
    char*  scratch = alloc((size_t)NBUCK * BCAP * 8);             // 16.1 MB (buckets / ha / hb)
    float* h0f    = (float*)alloc((size_t)N_NODES * PAD_C * 4);   // 12.8 MB
    unsigned short* h0b = (unsigned short*)alloc((size_t)N_NODES * PAD_C * 2); // 6.4 MB
    uint2* edges  = (uint2*)alloc((size_t)N_EDGES * 8);           // 12.8 MB packed CSR
    int*   rowptr = (int*)alloc((size_t)(N_NODES + 1) * 4);
    int*   bfill  = (int*)alloc((size_t)NBUCK * 4);
    int*   bbase  = (int*)alloc((size_t)(NBUCK + 1) * 4);
    float* bp     = (float*)alloc((size_t)PAD_C * 4);
    unsigned short* Wt  = (unsigned short*)alloc((size_t)HID_C * IN_C * 2);
    unsigned short* Wpt = (unsigned short*)alloc((size_t)PAD_C * HID_C * 2);
    // --- aliases onto scratch (sequential lifetimes, stream-ordered):
    uint2* buckets = (uint2*)scratch;                                       // CSR build
    unsigned short* ha = (unsigned short*)scratch;                          // 6.4 MB (prop)
    unsigned short* hb = (unsigned short*)(scratch + (size_t)N_NODES * PAD_C * 2); // 6.4 MB

    hipMemsetAsync(bfill, 0, (size_t)NBUCK * 4, stream);

    // CSR build (v3)
    bucket_scatter<<<PHB_BLOCKS, 256, 0, stream>>>(erow, ecol, ew, bfill, buckets);
    bucket_scan<<<1, 128, 0, stream>>>(bfill, bbase, rowptr);
    bucket_csr<<<NBUCK, 256, 0, stream>>>(buckets, bfill, bbase, rowptr, edges);

    // MLP (gemm2 fused into gemm1 epilogue; h_hid eliminated)
    transpose_w1<<<dim3(IN_C / 32, HID_C / 32), 256, 0, stream>>>(W1, Wt);
    pad_w2<<<(PAD_C * HID_C + 255) / 256, 256, 0, stream>>>(W2, b2, Wpt, bp);
    gemm1_fused<<<(N_NODES + 63) / 64, 256, 0, stream>>>(x, Wt, b1, Wpt, bp, h0f, h0b);

    // Propagation x10 (bf16 ping-pong; last layer fuses log_softmax -> out)
    const int prop_blocks = (N_NODES * 64 + 255) / 256;
    const unsigned short* cur = h0b;
    unsigned short* nxt = ha;
    for (int l = 0; l < NUM_LAYERS - 1; ++l) {
        prop8<false><<<prop_blocks, 256, 0, stream>>>(rowptr, edges, cur, h0f,
                                                      nxt, nullptr);
        const unsigned short* t = nxt;
        nxt = (nxt == ha) ? hb : ha;
        cur = t;
    }
    prop8<true><<<prop_blocks, 256, 0, stream>>>(rowptr, edges, cur, h0f,
                                                 nullptr, out);
}